// Round 5
// baseline (24.745 us; speedup 1.0000x reference)
//
#include <hip/hip_runtime.h>
#include <math.h>

#define NN 2048
#define RR 10
#define MM 2048
#define CC 84
#define IEPS 1e-7f
#define JB 512   // NN/4 : n-groups per r-slab in the balanced remap

// Kernel 1: one wave (64 lanes) per (n, r) pair.
// - Balanced remap: block B -> (r = B/JB, j = B%JB); wave w -> n = j + 512*w.
//   Each block mixes scan lengths {j, j+512, j+1024, j+1536} so the dispatch
//   tail is not all worst-case waves.
// - Software pipeline: issue chunk k+1's 4 loads BEFORE computing chunk k's
//   hits; serial per-iteration cost ~= compute only (~150 cyc), not
//   load-latency + compute.
// - Division-free: inter/(a1+a2-inter+eps) > 0.5 <=> 3*inter > a1+a2+eps.
// First set bit in m-order = first match (argmax-of-bool semantics).
__global__ __launch_bounds__(256) void match_kernel(
    const float* __restrict__ pred,
    const float* __restrict__ dpreds,
    int* __restrict__ first_idx) {
  int lane = threadIdx.x & 63;
  int w = threadIdx.x >> 6;          // wave in block, 0..3
  int B = blockIdx.x;
  int r = B / JB;                    // 0..9
  int j = B - r * JB;                // 0..511
  int n = j + (w << 9);              // j + 512*w  in [0, 2048)

  // pred row stride = 84 floats = 336 B (16B-aligned) -> float4 load OK
  float4 pb = *reinterpret_cast<const float4*>(pred + (size_t)n * CC);
  const float b1x1 = fmaf(-0.5f, pb.z, pb.x), b1x2 = fmaf(0.5f, pb.z, pb.x);
  const float b1y1 = fmaf(-0.5f, pb.w, pb.y), b1y2 = fmaf(0.5f, pb.w, pb.y);
  const float a1e = pb.z * pb.w + IEPS;  // area1 + eps

  const float4* __restrict__ dp =
      reinterpret_cast<const float4*>(dpreds + (size_t)r * MM * 4);

  // Prologue: chunk 0 in flight
  float4 c0 = dp[lane];
  float4 c1 = dp[64 + lane];
  float4 c2 = dp[128 + lane];
  float4 c3 = dp[192 + lane];

  int found = -1;
  for (int m0 = 0; m0 < MM; m0 += 256) {
    // Prefetch next chunk (clamped address; wasted only on the exit iter)
    int mb = m0 + 256 < MM ? m0 + 256 : m0;
    float4 p0 = dp[mb + lane];
    float4 p1 = dp[mb + 64 + lane];
    float4 p2 = dp[mb + 128 + lane];
    float4 p3 = dp[mb + 192 + lane];

#define HIT(db, h)                                                          \
    {                                                                       \
      float x1 = fmaf(-0.5f, db.z, db.x), x2 = fmaf(0.5f, db.z, db.x);      \
      float y1 = fmaf(-0.5f, db.w, db.y), y2 = fmaf(0.5f, db.w, db.y);      \
      float iw = fmaxf(fminf(b1x2, x2) - fmaxf(b1x1, x1), 0.0f);            \
      float ih = fmaxf(fminf(b1y2, y2) - fmaxf(b1y1, y1), 0.0f);            \
      float inter = iw * ih;                                                \
      float t = fmaf(db.z, db.w, a1e); /* a2 + a1 + eps */                  \
      h = (3.0f * inter > t);                                               \
    }
    bool h0, h1, h2, h3;
    HIT(c0, h0) HIT(c1, h1) HIT(c2, h2) HIT(c3, h3)
#undef HIT

    unsigned long long b0 = __ballot(h0);
    unsigned long long b1 = __ballot(h1);
    unsigned long long b2 = __ballot(h2);
    unsigned long long b3 = __ballot(h3);
    if (b0 | b1 | b2 | b3) {
      if (b0)      found = m0 +       (__ffsll(b0) - 1);
      else if (b1) found = m0 + 64  + (__ffsll(b1) - 1);
      else if (b2) found = m0 + 128 + (__ffsll(b2) - 1);
      else         found = m0 + 192 + (__ffsll(b3) - 1);
      break;
    }
    c0 = p0; c1 = p1; c2 = p2; c3 = p3;
  }
  if (lane == 0) first_idx[n * RR + r] = found;
}

// Kernel 2: one wave per n. Lane l handles classes l and l+64 (C=84).
// entropy[c] = sum_r -p log p over matched r; softmax over c; out = 1 - min(sm).
__global__ __launch_bounds__(256) void entropy_kernel(
    const float* __restrict__ confs,
    const int* __restrict__ first_idx,
    float* __restrict__ out) {
  int lane = threadIdx.x & 63;
  int n = blockIdx.x * (blockDim.x >> 6) + (threadIdx.x >> 6);
  if (n >= NN) return;

  int idxs[RR];
  bool anym = false;
#pragma unroll
  for (int r = 0; r < RR; ++r) {
    idxs[r] = first_idx[n * RR + r];
    anym = anym || (idxs[r] >= 0);
  }

  const bool has_hi = (lane + 64) < CC;  // lanes 0..19 carry a 2nd class
  float e0 = 0.0f, e1 = 0.0f;
#pragma unroll
  for (int r = 0; r < RR; ++r) {
    if (idxs[r] >= 0) {
      const float* row = confs + ((size_t)r * MM + (size_t)idxs[r]) * CC;
      float p0 = row[lane];
      e0 -= p0 * __logf(p0);
      if (has_hi) {
        float p1 = row[lane + 64];
        e1 -= p1 * __logf(p1);
      }
    }
  }

  float maxE = fmaxf(e0, has_hi ? e1 : -INFINITY);
  float minE = fminf(e0, has_hi ? e1 : INFINITY);
#pragma unroll
  for (int off = 32; off >= 1; off >>= 1) {
    maxE = fmaxf(maxE, __shfl_xor(maxE, off));
    minE = fminf(minE, __shfl_xor(minE, off));
  }
  float s = __expf(e0 - maxE) + (has_hi ? __expf(e1 - maxE) : 0.0f);
#pragma unroll
  for (int off = 32; off >= 1; off >>= 1) s += __shfl_xor(s, off);

  float result = anym ? (1.0f - __expf(minE - maxE) / s) : nanf("");
  if (lane == 0) out[n] = result;
}

extern "C" void kernel_launch(void* const* d_in, const int* in_sizes, int n_in,
                              void* d_out, int out_size, void* d_ws, size_t ws_size,
                              hipStream_t stream) {
  const float* pred   = (const float*)d_in[0];   // (N, 84)
  const float* dpreds = (const float*)d_in[1];   // (R, M, 4)
  const float* confs  = (const float*)d_in[2];   // (R, M, 84)
  float* out = (float*)d_out;                    // (N,)
  int* first_idx = (int*)d_ws;                   // N*R ints

  // Kernel 1: RR*JB blocks of 4 waves (balanced n-remap inside kernel)
  match_kernel<<<RR * JB, 256, 0, stream>>>(pred, dpreds, first_idx);
  // Kernel 2: one wave per n, 4 waves/block
  entropy_kernel<<<(NN + 3) / 4, 256, 0, stream>>>(confs, first_idx, out);
}